// Round 18
// baseline (70.991 us; speedup 1.0000x reference)
//
#include <hip/hip_runtime.h>
#include <hip/hip_bf16.h>

#define LOG2E 1.4426950408889634f
#define CHEB_R 4.0f          // domain [0,R] for both operands
#define CHEB_M 40            // degrees in each variable
#define CHEB_P 80            // transform sample nodes
#define PI_F 3.14159265358979f

typedef __attribute__((ext_vector_type(8))) short short8b;   // 8 bf16 (4 VGPR)
typedef __attribute__((ext_vector_type(4))) short short4b;   // 4 bf16 (8 B)
typedef __attribute__((ext_vector_type(4))) float f32x4;

__device__ __forceinline__ float fast_exp2(float x) {
#if __has_builtin(__builtin_amdgcn_exp2f)
  return __builtin_amdgcn_exp2f(x);
#else
  return exp2f(x);
#endif
}
__device__ __forceinline__ float fast_rcp(float x) {
#if __has_builtin(__builtin_amdgcn_rcpf)
  return __builtin_amdgcn_rcpf(x);
#else
  return 1.0f / x;
#endif
}
__device__ __forceinline__ short f2bf(float f) {
  __hip_bfloat16 h = __float2bfloat16(f);
  return *reinterpret_cast<short*>(&h);
}

// ---------------------------------------------------------------------------
// Stage 1: O = relu(X @ W^T + bias) via bf16 MFMA (r12-proven GEMM core);
// both z paths store dense f32 (compact machinery deleted).
// Tile 64x64, 4 waves (2x2).  grid (32, 8, 2) = 512 blocks = 2/CU.
// ---------------------------------------------------------------------------
__global__ __launch_bounds__(256) void gemm_kernel(
    const float* __restrict__ Xa, const float* __restrict__ Wa,
    const float* __restrict__ ba, float* __restrict__ Oa,
    const float* __restrict__ Xb, const float* __restrict__ Wb,
    const float* __restrict__ bb, float* __restrict__ Ob) {
  const int isB = blockIdx.z;
  const float* X = isB ? Xb : Xa;
  const float* W = isB ? Wb : Wa;
  const float* bias = isB ? bb : ba;
  float* O = isB ? Ob : Oa;

  __shared__ __align__(16) short As[64 * 40];  // 64 rows x 32 bf16 (+8 pad)
  __shared__ __align__(16) short Ws[64 * 40];

  int t = threadIdx.x;
  int m0 = blockIdx.x * 64, n0 = blockIdx.y * 64;
  int l = t & 63, w = t >> 6;
  int wm = (w >> 1) * 32, wn = (w & 1) * 32;
  int lr = l & 15, ko = (l >> 4) * 8;

  f32x4 acc[2][2];
#pragma unroll
  for (int m = 0; m < 2; ++m)
#pragma unroll
    for (int n = 0; n < 2; ++n) acc[m][n] = f32x4{0.f, 0.f, 0.f, 0.f};

  for (int k0 = 0; k0 < 512; k0 += 32) {
#pragma unroll
    for (int s = 0; s < 2; ++s) {
      int slot = t + s * 256;            // 512 slots: 64 rows x 8 quads
      int row = slot >> 3, qd = (slot & 7) << 2;
      float4 v = *reinterpret_cast<const float4*>(&X[(m0 + row) * 512 + k0 + qd]);
      short4b sv = {f2bf(v.x), f2bf(v.y), f2bf(v.z), f2bf(v.w)};
      *reinterpret_cast<short4b*>(&As[row * 40 + qd]) = sv;
      float4 u = *reinterpret_cast<const float4*>(&W[(n0 + row) * 512 + k0 + qd]);
      short4b su = {f2bf(u.x), f2bf(u.y), f2bf(u.z), f2bf(u.w)};
      *reinterpret_cast<short4b*>(&Ws[row * 40 + qd]) = su;
    }
    __syncthreads();

    short8b afr[2], bfr[2];
#pragma unroll
    for (int m = 0; m < 2; ++m)
      afr[m] = *reinterpret_cast<const short8b*>(&As[(wm + m * 16 + lr) * 40 + ko]);
#pragma unroll
    for (int n = 0; n < 2; ++n)
      bfr[n] = *reinterpret_cast<const short8b*>(&Ws[(wn + n * 16 + lr) * 40 + ko]);
#pragma unroll
    for (int m = 0; m < 2; ++m)
#pragma unroll
      for (int n = 0; n < 2; ++n)
        acc[m][n] = __builtin_amdgcn_mfma_f32_16x16x32_bf16(afr[m], bfr[n], acc[m][n], 0, 0, 0);
    __syncthreads();
  }

  // C/D layout: col = lane&15, row = (lane>>4)*4 + r
#pragma unroll
  for (int n = 0; n < 2; ++n) {
    int col = n0 + wn + n * 16 + lr;
    float bv = bias[col];
#pragma unroll
    for (int m = 0; m < 2; ++m) {
      int rbase = m0 + wm + m * 16 + (l >> 4) * 4;
#pragma unroll
      for (int r = 0; r < 4; ++r) {
        float v = acc[m][n][r] + bv;
        O[(rbase + r) * 512 + col] = v > 0.f ? v : 0.f;
      }
    }
  }
}

// ---------------------------------------------------------------------------
// Stage 2 (moments + coef): grid (65, 2, 4) x 256.
// Blocks bx<64: partial Chebyshev moments.  half=0: F from Ar; half=1: G
// from Br.  Raw-reshape: element (bh, idx, c) lives at
// row r = (bh>>3)*256 + (bh&7)*32 + (idx>>3), col = (idx&7)*64 + c.
// Block (bh, half, quad) covers colhi {2q, 2q+1} x 32 rows:
// thread t: c = t&63, colsel = t>>6 -> (colhi = 2q+(colsel&1),
// rowhalf = colsel>>1), 16 rows each.  acc[40] static-unrolled T-recurrence.
// Block bx==64 (y==0,z==0): computes the 40x40 Chebyshev coefficients of
// tanh(x*y) on [0,R]^2 via discrete transform of 80x80 tanhf samples.
// ---------------------------------------------------------------------------
__global__ __launch_bounds__(256) void moments_kernel(
    const float* __restrict__ Ar, const float* __restrict__ Br,
    float* __restrict__ Fpart, float* __restrict__ Gpart,
    float* __restrict__ cmn) {
  __shared__ __align__(16) float smem[13056];   // 52224 B, unioned

  int t = threadIdx.x;

  if (blockIdx.x == 64) {
    if (blockIdx.y != 0 || blockIdx.z != 0) return;
    // ---- coefficient block ----
    float* S = smem;            // [80][80]
    float* T = smem + 6400;     // [40][80]  T[n][q] = cos(n*theta_q)
    float* H = smem + 9600;     // [40][80]  H[n][p]
    for (int e = t; e < 6400; e += 256) {
      int p = e >> 6 ? e / 80 : e / 80;  // p = e/80
      p = e / 80;
      int qq = e - p * 80;
      float xp = CHEB_R * 0.5f * (1.f + cosf((2.f * p + 1.f) * (PI_F / 160.f)));
      float xq = CHEB_R * 0.5f * (1.f + cosf((2.f * qq + 1.f) * (PI_F / 160.f)));
      S[e] = tanhf(xp * xq);
    }
    for (int e = t; e < CHEB_M * 80; e += 256) {
      int n = e / 80, qq = e - n * 80;
      T[e] = cosf((float)n * (2.f * qq + 1.f) * (PI_F / 160.f));
    }
    __syncthreads();
    for (int e = t; e < CHEB_M * 80; e += 256) {
      int n = e / 80, p = e - n * 80;
      float s = 0.f;
      for (int qq = 0; qq < 80; ++qq) s = fmaf(T[n * 80 + qq], S[p * 80 + qq], s);
      H[n * 80 + p] = s;
    }
    __syncthreads();
    for (int e = t; e < CHEB_M * CHEB_M; e += 256) {
      int m = e / CHEB_M, n = e - m * CHEB_M;
      float s = 0.f;
      for (int p = 0; p < 80; ++p) s = fmaf(T[m * 80 + p], H[n * 80 + p], s);
      float wm = (m == 0) ? 1.f : 2.f;
      float wn = (n == 0) ? 1.f : 2.f;
      cmn[e] = s * (wm * wn / 6400.f);
    }
    return;
  }

  // ---- moments block ----
  float* red = smem;  // [4][40][64] = 10240 f
  int bh = blockIdx.x, half = blockIdx.y, quad = blockIdx.z;
  const float* X = half ? Br : Ar;
  float* Out = half ? Gpart : Fpart;
  int c = t & 63, colsel = t >> 6;
  int colhi = quad * 2 + (colsel & 1);
  int rowh = colsel >> 1;
  int rbase = (bh >> 3) * 256 + (bh & 7) * 32 + rowh * 16;
  const float* p = X + rbase * 512 + colhi * 64 + c;

  float acc[CHEB_M];
#pragma unroll
  for (int m = 0; m < CHEB_M; ++m) acc[m] = 0.f;

#pragma unroll 1
  for (int rr = 0; rr < 16; ++rr) {
    float a = p[rr * 512];
    float u = fminf(a * (2.f / CHEB_R) - 1.f, 1.f);   // a>=0 so u>=-1
    float tp = 1.f, tc = u;
    acc[0] += 1.f;
    acc[1] += u;
#pragma unroll
    for (int m = 2; m < CHEB_M; ++m) {
      float tn = fmaf(2.f * u, tc, -tp);
      acc[m] += tn;
      tp = tc; tc = tn;
    }
  }
#pragma unroll
  for (int m = 0; m < CHEB_M; ++m) red[(colsel * CHEB_M + m) * 64 + c] = acc[m];
  __syncthreads();
  for (int e = t; e < CHEB_M * 64; e += 256) {
    int m = e >> 6, cc = e & 63;
    float s = red[(0 * CHEB_M + m) * 64 + cc] + red[(1 * CHEB_M + m) * 64 + cc] +
              red[(2 * CHEB_M + m) * 64 + cc] + red[(3 * CHEB_M + m) * 64 + cc];
    Out[(((bh * 4 + quad) * CHEB_M) + m) * 64 + cc] = s;
  }
}

// ---------------------------------------------------------------------------
// Stage 3 (finalize): grid (64 bh, 4 qd) x 512.
// Per block: sum the 4 quad-partials of F,G; gq[m][c] = (q_c/256) *
// sum_n cmn[m][n] G[n][c];  dq[n][c] = (q_c/256) * sum_m cmn[m][n] F[m][c].
// rowmean_i = sum_c sum_m T_m(u(A_ic)) gq[m][c]   (i in qd's 64-range)
// colmean_j = sum_c sum_n T_n(u(B_jc)) dq[n][c]
// ---------------------------------------------------------------------------
__global__ __launch_bounds__(512) void finalize_kernel(
    const float* __restrict__ Ar, const float* __restrict__ Br,
    const float* __restrict__ Fpart, const float* __restrict__ Gpart,
    const float* __restrict__ cmn, const float* __restrict__ q,
    float* __restrict__ rowmean, float* __restrict__ colmean) {
  __shared__ float cs[CHEB_M * CHEB_M];    // 1600
  __shared__ float Fs[CHEB_M * 64];        // 2560
  __shared__ float Gs[CHEB_M * 64];
  __shared__ float gq[CHEB_M * 64];
  __shared__ float dq[CHEB_M * 64];

  int bh = blockIdx.x, qd = blockIdx.y;
  int t = threadIdx.x;

  for (int e = t; e < CHEB_M * CHEB_M; e += 512) cs[e] = cmn[e];
  for (int e = t; e < CHEB_M * 64; e += 512) {
    float f = 0.f, g = 0.f;
#pragma unroll
    for (int p = 0; p < 4; ++p) {
      f += Fpart[((bh * 4 + p) * CHEB_M) * 64 + e];
      g += Gpart[((bh * 4 + p) * CHEB_M) * 64 + e];
    }
    Fs[e] = f; Gs[e] = g;
  }
  __syncthreads();

  for (int e = t; e < CHEB_M * 64; e += 512) {
    int m = e >> 6, c = e & 63;
    float qc = q[c] * (1.f / 256.f);
    float sg = 0.f, sd = 0.f;
    for (int n = 0; n < CHEB_M; ++n) {
      sg = fmaf(cs[m * CHEB_M + n], Gs[n * 64 + c], sg);   // gq: m couples A
      sd = fmaf(cs[n * CHEB_M + m], Fs[n * 64 + c], sd);   // dq[m][c] uses c_nm
    }
    gq[e] = sg * qc;
    dq[e] = sd * qc;
  }
  __syncthreads();

  int rbase = (bh >> 3) * 256 + (bh & 7) * 32;
  // rows
  {
    int i = qd * 64 + (t >> 3);
    int ce = t & 7;
    const float* base = Ar + (rbase + (i >> 3)) * 512 + (i & 7) * 64;
    float s = 0.f;
#pragma unroll 1
    for (int cc = 0; cc < 8; ++cc) {
      int c = ce * 8 + cc;
      float a = base[c];
      float u = fminf(a * (2.f / CHEB_R) - 1.f, 1.f);
      float tp = 1.f, tc = u;
      s += gq[0 * 64 + c];
      s = fmaf(gq[1 * 64 + c], u, s);
#pragma unroll
      for (int m = 2; m < CHEB_M; ++m) {
        float tn = fmaf(2.f * u, tc, -tp);
        s = fmaf(gq[m * 64 + c], tn, s);
        tp = tc; tc = tn;
      }
    }
    s += __shfl_xor(s, 1);
    s += __shfl_xor(s, 2);
    s += __shfl_xor(s, 4);
    if ((t & 7) == 0) rowmean[bh * 256 + i] = s;
  }
  // cols
  {
    int j = qd * 64 + (t >> 3);
    int ce = t & 7;
    const float* base = Br + (rbase + (j >> 3)) * 512 + (j & 7) * 64;
    float s = 0.f;
#pragma unroll 1
    for (int cc = 0; cc < 8; ++cc) {
      int c = ce * 8 + cc;
      float b = base[c];
      float u = fminf(b * (2.f / CHEB_R) - 1.f, 1.f);
      float tp = 1.f, tc = u;
      s += dq[0 * 64 + c];
      s = fmaf(dq[1 * 64 + c], u, s);
#pragma unroll
      for (int m = 2; m < CHEB_M; ++m) {
        float tn = fmaf(2.f * u, tc, -tp);
        s = fmaf(dq[m * 64 + c], tn, s);
        tp = tc; tc = tn;
      }
    }
    s += __shfl_xor(s, 1);
    s += __shfl_xor(s, 2);
    s += __shfl_xor(s, 4);
    if ((t & 7) == 0) colmean[bh * 256 + j] = s;
  }
}

// ---------------------------------------------------------------------------
// Stage 4 (r12-proven softmax_pool; inputs are now direct row/col means):
// grid (64 bh, 4 chunk), 512 thr.  chunk 0 writes b2a/a2b temps.
// ---------------------------------------------------------------------------
__global__ __launch_bounds__(512) void softmax_pool_kernel(
    const float* __restrict__ rowmean, const float* __restrict__ colmean,
    const float* __restrict__ A0, const float* __restrict__ B0,
    float* __restrict__ b2a, float* __restrict__ a2b,
    float* __restrict__ poolA, float* __restrict__ poolB) {
  int bh = blockIdx.x, chunk = blockIdx.y;
  int b = bh >> 3, h = bh & 7;
  int t = threadIdx.x;
  int tt = t & 255;
  int lane = t & 63, w = (t >> 6) & 3;
  __shared__ float redA[4], redB[4], redC[4], redD[4];
  __shared__ float tA[256], tB[256];
  __shared__ float pp[8][64];

  float r = rowmean[bh * 256 + tt];
  float cs = colmean[bh * 256 + tt];

  float mr = r, mc = cs;
#pragma unroll
  for (int off = 32; off >= 1; off >>= 1) {
    mr = fmaxf(mr, __shfl_xor(mr, off));
    mc = fmaxf(mc, __shfl_xor(mc, off));
  }
  if (lane == 0) { redA[w] = mr; redB[w] = mc; }
  __syncthreads();
  mr = fmaxf(fmaxf(redA[0], redA[1]), fmaxf(redA[2], redA[3]));
  mc = fmaxf(fmaxf(redB[0], redB[1]), fmaxf(redB[2], redB[3]));

  float er = fast_exp2((r - mr) * LOG2E);
  float ec = fast_exp2((cs - mc) * LOG2E);
  float sr = er, sc = ec;
#pragma unroll
  for (int off = 32; off >= 1; off >>= 1) {
    sr += __shfl_xor(sr, off);
    sc += __shfl_xor(sc, off);
  }
  if (lane == 0) { redC[w] = sr; redD[w] = sc; }
  __syncthreads();
  sr = redC[0] + redC[1] + redC[2] + redC[3];
  sc = redD[0] + redD[1] + redD[2] + redD[3];

  float vb2a = er * fast_rcp(sr);
  float va2b = ec * fast_rcp(sc);
  tA[tt] = vb2a; tB[tt] = va2b;
  if (chunk == 0) {
    b2a[bh * 256 + tt] = vb2a;
    a2b[bh * 256 + tt] = va2b;
  }
  __syncthreads();

  int c = t & 63, isub = t >> 6;
  const float* Ab = A0 + b * 131072 + h * 16384;
  const float* Bb = B0 + b * 131072 + h * 16384;
  float pa = 0.f, pb = 0.f;
#pragma unroll
  for (int ii = 0; ii < 8; ++ii) {
    int i = chunk * 64 + isub * 8 + ii;
    pa = fmaf(Ab[i * 64 + c], tA[i], pa);
    pb = fmaf(Bb[i * 64 + c], tB[i], pb);
  }
  pp[isub][c] = pa;
  __syncthreads();
  if (t < 64) {
    float s = 0.f;
#pragma unroll
    for (int k = 0; k < 8; ++k) s += pp[k][t];
    poolA[(bh * 4 + chunk) * 64 + t] = s;
  }
  __syncthreads();
  pp[isub][c] = pb;
  __syncthreads();
  if (t < 64) {
    float s = 0.f;
#pragma unroll
    for (int k = 0; k < 8; ++k) s += pp[k][t];
    poolB[(bh * 4 + chunk) * 64 + t] = s;
  }
}

// ---------------------------------------------------------------------------
// Stage 5 (r12-verbatim): combine pool partials + head-means.  grid 8 x 256.
// ---------------------------------------------------------------------------
__global__ __launch_bounds__(256) void final_kernel(
    const float* __restrict__ poolA, const float* __restrict__ poolB,
    const float* __restrict__ b2a, const float* __restrict__ a2b,
    float* __restrict__ out) {
  int b = blockIdx.x, t = threadIdx.x;
  float s1 = 0.f, s2 = 0.f;
#pragma unroll
  for (int h = 0; h < 8; ++h) {
    s1 += b2a[(b * 8 + h) * 256 + t];
    s2 += a2b[(b * 8 + h) * 256 + t];
  }
  out[8192 + b * 256 + t] = s1 * 0.125f;
  out[10240 + b * 256 + t] = s2 * 0.125f;

#pragma unroll
  for (int hh = 0; hh < 2; ++hh) {
    int idx = hh * 256 + t;
    int h = idx >> 6, c = idx & 63;
    int base = ((b * 8 + h) * 4) * 64 + c;
    float sA = poolA[base] + poolA[base + 64] + poolA[base + 128] + poolA[base + 192];
    float sB = poolB[base] + poolB[base + 64] + poolB[base + 128] + poolB[base + 192];
    out[b * 1024 + h * 64 + c] = sA;
    out[b * 1024 + 512 + h * 64 + c] = sB;
  }
}

extern "C" void kernel_launch(void* const* d_in, const int* in_sizes, int n_in,
                              void* d_out, int out_size, void* d_ws, size_t ws_size,
                              hipStream_t stream) {
  const float* A  = (const float*)d_in[0];
  const float* B  = (const float*)d_in[1];
  const float* W1 = (const float*)d_in[2];
  const float* b1 = (const float*)d_in[3];
  const float* W2 = (const float*)d_in[4];
  const float* b2 = (const float*)d_in[5];
  const float* q  = (const float*)d_in[6];
  float* out = (float*)d_out;
  float* ws = (float*)d_ws;

  float* Ar      = ws;                 // 1,048,576 f
  float* Br      = ws + 1048576;       // 1,048,576 f
  float* Fpart   = ws + 2097152;       // 64*4*40*64 = 655,360 f
  float* Gpart   = ws + 2752512;       // 655,360 f
  float* cmn     = ws + 3407872;       // 1,600 f
  float* rowmean = ws + 3409472;       // 16,384 f
  float* colmean = ws + 3425856;       // 16,384 f
  float* b2a     = ws + 3442240;       // 16,384 f
  float* a2b     = ws + 3458624;       // 16,384 f
  float* poolA   = ws + 3475008;       // 16,384 f
  float* poolB   = ws + 3491392;       // 16,384 f  (end ~14.0 MB)

  gemm_kernel<<<dim3(32, 8, 2), 256, 0, stream>>>(A, W1, b1, Ar, B, W2, b2, Br);
  moments_kernel<<<dim3(65, 2, 4), 256, 0, stream>>>(Ar, Br, Fpart, Gpart, cmn);
  finalize_kernel<<<dim3(64, 4), 512, 0, stream>>>(Ar, Br, Fpart, Gpart, cmn, q,
                                                   rowmean, colmean);
  softmax_pool_kernel<<<dim3(64, 4), 512, 0, stream>>>(
      rowmean, colmean, A, B, b2a, a2b, poolA, poolB);
  final_kernel<<<8, 256, 0, stream>>>(poolA, poolB, b2a, a2b, out);
}

// Round 19
// 69.539 us; speedup vs baseline: 1.0209x; 1.0209x over previous
//
#include <hip/hip_runtime.h>
#include <hip/hip_bf16.h>

#define LOG2E 1.4426950408889634f
#define SC2   2.8853900817779268f   // 2*log2(e)
#define CHEB_R 4.0f
#define CHEB_M 40
#define PI_F 3.14159265358979f

typedef __attribute__((ext_vector_type(8))) short short8b;
typedef __attribute__((ext_vector_type(4))) short short4b;
typedef __attribute__((ext_vector_type(4))) float f32x4;

__device__ __forceinline__ float fast_exp2(float x) {
#if __has_builtin(__builtin_amdgcn_exp2f)
  return __builtin_amdgcn_exp2f(x);
#else
  return exp2f(x);
#endif
}
__device__ __forceinline__ float fast_rcp(float x) {
#if __has_builtin(__builtin_amdgcn_rcpf)
  return __builtin_amdgcn_rcpf(x);
#else
  return 1.0f / x;
#endif
}
__device__ __forceinline__ short f2bf(float f) {
  __hip_bfloat16 h = __float2bfloat16(f);
  return *reinterpret_cast<short*>(&h);
}

// ---------------------------------------------------------------------------
// Stage 1: gemm (r12 core) + coef side-block.
// z<2: O = relu(X @ W^T + bias) via bf16 MFMA, 64x64 tile, dense f32 store.
// z==2 (block (0,0) only): 40x40 Chebyshev coefficients of tanh(x*y) on
// [0,R]^2 via 80x80 discrete transform; tanh via exp2 identity (fast),
// runs concurrently under the 512 gemm blocks.
// ---------------------------------------------------------------------------
__global__ __launch_bounds__(256) void gemm_coef_kernel(
    const float* __restrict__ Xa, const float* __restrict__ Wa,
    const float* __restrict__ ba, float* __restrict__ Oa,
    const float* __restrict__ Xb, const float* __restrict__ Wb,
    const float* __restrict__ bb, float* __restrict__ Ob,
    float* __restrict__ cmn) {
  __shared__ __align__(16) char smem_raw[51712];
  int t = threadIdx.x;

  if (blockIdx.z == 2) {
    if (blockIdx.x != 0 || blockIdx.y != 0) return;
    float* S = (float*)smem_raw;        // [80][80]
    float* T = S + 6400;                // [40][80]
    float* H = S + 9600;                // [40][80]
    float* xn = S + 12800;              // [80]
    if (t < 80) xn[t] = CHEB_R * 0.5f * (1.f + cosf((2.f * t + 1.f) * (PI_F / 160.f)));
    __syncthreads();
    for (int e = t; e < 6400; e += 256) {
      int p = e / 80, qq = e - p * 80;
      float x = xn[p] * xn[qq];
      float ee = fast_exp2(x * SC2);            // e^{2x}
      S[e] = (ee - 1.f) * fast_rcp(ee + 1.f);   // tanh(x)
    }
    for (int e = t; e < CHEB_M * 80; e += 256) {
      int n = e / 80, qq = e - n * 80;
      T[e] = cosf((float)n * (2.f * qq + 1.f) * (PI_F / 160.f));
    }
    __syncthreads();
    for (int e = t; e < CHEB_M * 80; e += 256) {
      int n = e / 80, p = e - n * 80;
      float s = 0.f;
      for (int qq = 0; qq < 80; ++qq) s = fmaf(T[n * 80 + qq], S[p * 80 + qq], s);
      H[n * 80 + p] = s;
    }
    __syncthreads();
    for (int e = t; e < CHEB_M * CHEB_M; e += 256) {
      int m = e / CHEB_M, n = e - m * CHEB_M;
      float s = 0.f;
      for (int p = 0; p < 80; ++p) s = fmaf(T[m * 80 + p], H[n * 80 + p], s);
      float wm = (m == 0) ? 1.f : 2.f;
      float wn = (n == 0) ? 1.f : 2.f;
      cmn[e] = s * (wm * wn / 6400.f);
    }
    return;
  }

  const int isB = blockIdx.z;
  const float* X = isB ? Xb : Xa;
  const float* W = isB ? Wb : Wa;
  const float* bias = isB ? bb : ba;
  float* O = isB ? Ob : Oa;

  short* As = (short*)smem_raw;          // 64 x 40 bf16
  short* Ws = As + 64 * 40;

  int m0 = blockIdx.x * 64, n0 = blockIdx.y * 64;
  int l = t & 63, w = t >> 6;
  int wm = (w >> 1) * 32, wn = (w & 1) * 32;
  int lr = l & 15, ko = (l >> 4) * 8;

  f32x4 acc[2][2];
#pragma unroll
  for (int m = 0; m < 2; ++m)
#pragma unroll
    for (int n = 0; n < 2; ++n) acc[m][n] = f32x4{0.f, 0.f, 0.f, 0.f};

  for (int k0 = 0; k0 < 512; k0 += 32) {
#pragma unroll
    for (int s = 0; s < 2; ++s) {
      int slot = t + s * 256;
      int row = slot >> 3, qd = (slot & 7) << 2;
      float4 v = *reinterpret_cast<const float4*>(&X[(m0 + row) * 512 + k0 + qd]);
      short4b sv = {f2bf(v.x), f2bf(v.y), f2bf(v.z), f2bf(v.w)};
      *reinterpret_cast<short4b*>(&As[row * 40 + qd]) = sv;
      float4 u = *reinterpret_cast<const float4*>(&W[(n0 + row) * 512 + k0 + qd]);
      short4b su = {f2bf(u.x), f2bf(u.y), f2bf(u.z), f2bf(u.w)};
      *reinterpret_cast<short4b*>(&Ws[row * 40 + qd]) = su;
    }
    __syncthreads();

    short8b afr[2], bfr[2];
#pragma unroll
    for (int m = 0; m < 2; ++m)
      afr[m] = *reinterpret_cast<const short8b*>(&As[(wm + m * 16 + lr) * 40 + ko]);
#pragma unroll
    for (int n = 0; n < 2; ++n)
      bfr[n] = *reinterpret_cast<const short8b*>(&Ws[(wn + n * 16 + lr) * 40 + ko]);
#pragma unroll
    for (int m = 0; m < 2; ++m)
#pragma unroll
      for (int n = 0; n < 2; ++n)
        acc[m][n] = __builtin_amdgcn_mfma_f32_16x16x32_bf16(afr[m], bfr[n], acc[m][n], 0, 0, 0);
    __syncthreads();
  }

#pragma unroll
  for (int n = 0; n < 2; ++n) {
    int col = n0 + wn + n * 16 + lr;
    float bv = bias[col];
#pragma unroll
    for (int m = 0; m < 2; ++m) {
      int rbase = m0 + wm + m * 16 + (l >> 4) * 4;
#pragma unroll
      for (int r = 0; r < 4; ++r) {
        float v = acc[m][n][r] + bv;
        O[(rbase + r) * 512 + col] = v > 0.f ? v : 0.f;
      }
    }
  }
}

// ---------------------------------------------------------------------------
// Stage 2 (moments, ILP-4): grid (64, 2, 4) x 256.  half=0: F from Ar;
// half=1: G from Br.  Raw-reshape: (bh, idx, c) at row (bh>>3)*256 +
// (bh&7)*32 + (idx>>3), col (idx&7)*64 + c.  4 independent T-recurrence
// chains per iteration hide dependency latency.
// ---------------------------------------------------------------------------
__global__ __launch_bounds__(256) void moments_kernel(
    const float* __restrict__ Ar, const float* __restrict__ Br,
    float* __restrict__ Fpart, float* __restrict__ Gpart) {
  __shared__ float red[4 * CHEB_M * 64];   // 40960 B
  int t = threadIdx.x;
  int bh = blockIdx.x, half = blockIdx.y, quad = blockIdx.z;
  const float* X = half ? Br : Ar;
  float* Out = half ? Gpart : Fpart;
  int c = t & 63, colsel = t >> 6;
  int colhi = quad * 2 + (colsel & 1);
  int rowh = colsel >> 1;
  int rbase = (bh >> 3) * 256 + (bh & 7) * 32 + rowh * 16;
  const float* p = X + rbase * 512 + colhi * 64 + c;

  float acc[CHEB_M];
#pragma unroll
  for (int m = 0; m < CHEB_M; ++m) acc[m] = 0.f;

#pragma unroll 1
  for (int rr = 0; rr < 16; rr += 4) {
    float a0 = p[(rr + 0) * 512];
    float a1 = p[(rr + 1) * 512];
    float a2 = p[(rr + 2) * 512];
    float a3 = p[(rr + 3) * 512];
    float u0 = fminf(a0 * 0.5f - 1.f, 1.f);
    float u1 = fminf(a1 * 0.5f - 1.f, 1.f);
    float u2 = fminf(a2 * 0.5f - 1.f, 1.f);
    float u3 = fminf(a3 * 0.5f - 1.f, 1.f);
    acc[0] += 4.f;
    acc[1] += (u0 + u1) + (u2 + u3);
    float tp0 = 1.f, tc0 = u0, tp1 = 1.f, tc1 = u1;
    float tp2 = 1.f, tc2 = u2, tp3 = 1.f, tc3 = u3;
#pragma unroll
    for (int m = 2; m < CHEB_M; ++m) {
      float tn0 = fmaf(2.f * u0, tc0, -tp0);
      float tn1 = fmaf(2.f * u1, tc1, -tp1);
      float tn2 = fmaf(2.f * u2, tc2, -tp2);
      float tn3 = fmaf(2.f * u3, tc3, -tp3);
      acc[m] += (tn0 + tn1) + (tn2 + tn3);
      tp0 = tc0; tc0 = tn0; tp1 = tc1; tc1 = tn1;
      tp2 = tc2; tc2 = tn2; tp3 = tc3; tc3 = tn3;
    }
  }
#pragma unroll
  for (int m = 0; m < CHEB_M; ++m) red[(colsel * CHEB_M + m) * 64 + c] = acc[m];
  __syncthreads();
  for (int e = t; e < CHEB_M * 64; e += 256) {
    int m = e >> 6, cc = e & 63;
    float s = red[(0 * CHEB_M + m) * 64 + cc] + red[(1 * CHEB_M + m) * 64 + cc] +
              red[(2 * CHEB_M + m) * 64 + cc] + red[(3 * CHEB_M + m) * 64 + cc];
    Out[(((bh * 4 + quad) * CHEB_M) + m) * 64 + cc] = s;
  }
}

// ---------------------------------------------------------------------------
// Stage 3 (finalize, ILP-4): grid (64 bh, 4 qd) x 512.
// gq[m][c] = (q_c/256) sum_n cmn[m][n] G[n][c]; dq sym. with F and c_nm.
// rowmean_i = sum_c sum_m T_m(u(A_ic)) gq[m][c]; colmean_j analog.
// 4 independent recurrence chains + 4 accumulators per thread.
// ---------------------------------------------------------------------------
__global__ __launch_bounds__(512) void finalize_kernel(
    const float* __restrict__ Ar, const float* __restrict__ Br,
    const float* __restrict__ Fpart, const float* __restrict__ Gpart,
    const float* __restrict__ cmn, const float* __restrict__ q,
    float* __restrict__ rowmean, float* __restrict__ colmean) {
  __shared__ float cs[CHEB_M * CHEB_M];
  __shared__ float Fs[CHEB_M * 64];
  __shared__ float Gs[CHEB_M * 64];
  __shared__ float gq[CHEB_M * 64];
  __shared__ float dq[CHEB_M * 64];

  int bh = blockIdx.x, qd = blockIdx.y;
  int t = threadIdx.x;

  for (int e = t; e < CHEB_M * CHEB_M; e += 512) cs[e] = cmn[e];
  for (int e = t; e < CHEB_M * 64; e += 512) {
    float f = 0.f, g = 0.f;
#pragma unroll
    for (int p = 0; p < 4; ++p) {
      f += Fpart[((bh * 4 + p) * CHEB_M) * 64 + e];
      g += Gpart[((bh * 4 + p) * CHEB_M) * 64 + e];
    }
    Fs[e] = f; Gs[e] = g;
  }
  __syncthreads();

  for (int e = t; e < CHEB_M * 64; e += 512) {
    int m = e >> 6, c = e & 63;
    float qc = q[c] * (1.f / 256.f);
    float sg = 0.f, sd = 0.f;
    for (int n = 0; n < CHEB_M; ++n) {
      sg = fmaf(cs[m * CHEB_M + n], Gs[n * 64 + c], sg);
      sd = fmaf(cs[n * CHEB_M + m], Fs[n * 64 + c], sd);
    }
    gq[e] = sg * qc;
    dq[e] = sd * qc;
  }
  __syncthreads();

  int rbase = (bh >> 3) * 256 + (bh & 7) * 32;
  // rows
  {
    int i = qd * 64 + (t >> 3);
    int ce = t & 7;
    const float* base = Ar + (rbase + (i >> 3)) * 512 + (i & 7) * 64 + ce * 8;
    float s0 = 0.f, s1 = 0.f, s2 = 0.f, s3 = 0.f;
#pragma unroll
    for (int g4 = 0; g4 < 2; ++g4) {
      int c0 = ce * 8 + g4 * 4;
      float a0 = base[g4 * 4 + 0], a1 = base[g4 * 4 + 1];
      float a2 = base[g4 * 4 + 2], a3 = base[g4 * 4 + 3];
      float u0 = fminf(a0 * 0.5f - 1.f, 1.f);
      float u1 = fminf(a1 * 0.5f - 1.f, 1.f);
      float u2 = fminf(a2 * 0.5f - 1.f, 1.f);
      float u3 = fminf(a3 * 0.5f - 1.f, 1.f);
      s0 += gq[c0 + 0]; s1 += gq[c0 + 1]; s2 += gq[c0 + 2]; s3 += gq[c0 + 3];
      s0 = fmaf(gq[64 + c0 + 0], u0, s0);
      s1 = fmaf(gq[64 + c0 + 1], u1, s1);
      s2 = fmaf(gq[64 + c0 + 2], u2, s2);
      s3 = fmaf(gq[64 + c0 + 3], u3, s3);
      float tp0 = 1.f, tc0 = u0, tp1 = 1.f, tc1 = u1;
      float tp2 = 1.f, tc2 = u2, tp3 = 1.f, tc3 = u3;
#pragma unroll
      for (int m = 2; m < CHEB_M; ++m) {
        float tn0 = fmaf(2.f * u0, tc0, -tp0);
        float tn1 = fmaf(2.f * u1, tc1, -tp1);
        float tn2 = fmaf(2.f * u2, tc2, -tp2);
        float tn3 = fmaf(2.f * u3, tc3, -tp3);
        s0 = fmaf(gq[m * 64 + c0 + 0], tn0, s0);
        s1 = fmaf(gq[m * 64 + c0 + 1], tn1, s1);
        s2 = fmaf(gq[m * 64 + c0 + 2], tn2, s2);
        s3 = fmaf(gq[m * 64 + c0 + 3], tn3, s3);
        tp0 = tc0; tc0 = tn0; tp1 = tc1; tc1 = tn1;
        tp2 = tc2; tc2 = tn2; tp3 = tc3; tc3 = tn3;
      }
    }
    float s = (s0 + s1) + (s2 + s3);
    s += __shfl_xor(s, 1);
    s += __shfl_xor(s, 2);
    s += __shfl_xor(s, 4);
    if ((t & 7) == 0) rowmean[bh * 256 + i] = s;
  }
  // cols
  {
    int j = qd * 64 + (t >> 3);
    int ce = t & 7;
    const float* base = Br + (rbase + (j >> 3)) * 512 + (j & 7) * 64 + ce * 8;
    float s0 = 0.f, s1 = 0.f, s2 = 0.f, s3 = 0.f;
#pragma unroll
    for (int g4 = 0; g4 < 2; ++g4) {
      int c0 = ce * 8 + g4 * 4;
      float a0 = base[g4 * 4 + 0], a1 = base[g4 * 4 + 1];
      float a2 = base[g4 * 4 + 2], a3 = base[g4 * 4 + 3];
      float u0 = fminf(a0 * 0.5f - 1.f, 1.f);
      float u1 = fminf(a1 * 0.5f - 1.f, 1.f);
      float u2 = fminf(a2 * 0.5f - 1.f, 1.f);
      float u3 = fminf(a3 * 0.5f - 1.f, 1.f);
      s0 += dq[c0 + 0]; s1 += dq[c0 + 1]; s2 += dq[c0 + 2]; s3 += dq[c0 + 3];
      s0 = fmaf(dq[64 + c0 + 0], u0, s0);
      s1 = fmaf(dq[64 + c0 + 1], u1, s1);
      s2 = fmaf(dq[64 + c0 + 2], u2, s2);
      s3 = fmaf(dq[64 + c0 + 3], u3, s3);
      float tp0 = 1.f, tc0 = u0, tp1 = 1.f, tc1 = u1;
      float tp2 = 1.f, tc2 = u2, tp3 = 1.f, tc3 = u3;
#pragma unroll
      for (int m = 2; m < CHEB_M; ++m) {
        float tn0 = fmaf(2.f * u0, tc0, -tp0);
        float tn1 = fmaf(2.f * u1, tc1, -tp1);
        float tn2 = fmaf(2.f * u2, tc2, -tp2);
        float tn3 = fmaf(2.f * u3, tc3, -tp3);
        s0 = fmaf(dq[m * 64 + c0 + 0], tn0, s0);
        s1 = fmaf(dq[m * 64 + c0 + 1], tn1, s1);
        s2 = fmaf(dq[m * 64 + c0 + 2], tn2, s2);
        s3 = fmaf(dq[m * 64 + c0 + 3], tn3, s3);
        tp0 = tc0; tc0 = tn0; tp1 = tc1; tc1 = tn1;
        tp2 = tc2; tc2 = tn2; tp3 = tc3; tc3 = tn3;
      }
    }
    float s = (s0 + s1) + (s2 + s3);
    s += __shfl_xor(s, 1);
    s += __shfl_xor(s, 2);
    s += __shfl_xor(s, 4);
    if ((t & 7) == 0) colmean[bh * 256 + j] = s;
  }
}

// ---------------------------------------------------------------------------
// Stage 4 (r12-proven): grid (64 bh, 4 chunk), 512 thr.
// ---------------------------------------------------------------------------
__global__ __launch_bounds__(512) void softmax_pool_kernel(
    const float* __restrict__ rowmean, const float* __restrict__ colmean,
    const float* __restrict__ A0, const float* __restrict__ B0,
    float* __restrict__ b2a, float* __restrict__ a2b,
    float* __restrict__ poolA, float* __restrict__ poolB) {
  int bh = blockIdx.x, chunk = blockIdx.y;
  int b = bh >> 3, h = bh & 7;
  int t = threadIdx.x;
  int tt = t & 255;
  int lane = t & 63, w = (t >> 6) & 3;
  __shared__ float redA[4], redB[4], redC[4], redD[4];
  __shared__ float tA[256], tB[256];
  __shared__ float pp[8][64];

  float r = rowmean[bh * 256 + tt];
  float cs = colmean[bh * 256 + tt];

  float mr = r, mc = cs;
#pragma unroll
  for (int off = 32; off >= 1; off >>= 1) {
    mr = fmaxf(mr, __shfl_xor(mr, off));
    mc = fmaxf(mc, __shfl_xor(mc, off));
  }
  if (lane == 0) { redA[w] = mr; redB[w] = mc; }
  __syncthreads();
  mr = fmaxf(fmaxf(redA[0], redA[1]), fmaxf(redA[2], redA[3]));
  mc = fmaxf(fmaxf(redB[0], redB[1]), fmaxf(redB[2], redB[3]));

  float er = fast_exp2((r - mr) * LOG2E);
  float ec = fast_exp2((cs - mc) * LOG2E);
  float sr = er, sc = ec;
#pragma unroll
  for (int off = 32; off >= 1; off >>= 1) {
    sr += __shfl_xor(sr, off);
    sc += __shfl_xor(sc, off);
  }
  if (lane == 0) { redC[w] = sr; redD[w] = sc; }
  __syncthreads();
  sr = redC[0] + redC[1] + redC[2] + redC[3];
  sc = redD[0] + redD[1] + redD[2] + redD[3];

  float vb2a = er * fast_rcp(sr);
  float va2b = ec * fast_rcp(sc);
  tA[tt] = vb2a; tB[tt] = va2b;
  if (chunk == 0) {
    b2a[bh * 256 + tt] = vb2a;
    a2b[bh * 256 + tt] = va2b;
  }
  __syncthreads();

  int c = t & 63, isub = t >> 6;
  const float* Ab = A0 + b * 131072 + h * 16384;
  const float* Bb = B0 + b * 131072 + h * 16384;
  float pa = 0.f, pb = 0.f;
#pragma unroll
  for (int ii = 0; ii < 8; ++ii) {
    int i = chunk * 64 + isub * 8 + ii;
    pa = fmaf(Ab[i * 64 + c], tA[i], pa);
    pb = fmaf(Bb[i * 64 + c], tB[i], pb);
  }
  pp[isub][c] = pa;
  __syncthreads();
  if (t < 64) {
    float s = 0.f;
#pragma unroll
    for (int k = 0; k < 8; ++k) s += pp[k][t];
    poolA[(bh * 4 + chunk) * 64 + t] = s;
  }
  __syncthreads();
  pp[isub][c] = pb;
  __syncthreads();
  if (t < 64) {
    float s = 0.f;
#pragma unroll
    for (int k = 0; k < 8; ++k) s += pp[k][t];
    poolB[(bh * 4 + chunk) * 64 + t] = s;
  }
}

// ---------------------------------------------------------------------------
// Stage 5 (r12-verbatim): combine pool partials + head-means.  grid 8 x 256.
// ---------------------------------------------------------------------------
__global__ __launch_bounds__(256) void final_kernel(
    const float* __restrict__ poolA, const float* __restrict__ poolB,
    const float* __restrict__ b2a, const float* __restrict__ a2b,
    float* __restrict__ out) {
  int b = blockIdx.x, t = threadIdx.x;
  float s1 = 0.f, s2 = 0.f;
#pragma unroll
  for (int h = 0; h < 8; ++h) {
    s1 += b2a[(b * 8 + h) * 256 + t];
    s2 += a2b[(b * 8 + h) * 256 + t];
  }
  out[8192 + b * 256 + t] = s1 * 0.125f;
  out[10240 + b * 256 + t] = s2 * 0.125f;

#pragma unroll
  for (int hh = 0; hh < 2; ++hh) {
    int idx = hh * 256 + t;
    int h = idx >> 6, c = idx & 63;
    int base = ((b * 8 + h) * 4) * 64 + c;
    float sA = poolA[base] + poolA[base + 64] + poolA[base + 128] + poolA[base + 192];
    float sB = poolB[base] + poolB[base + 64] + poolB[base + 128] + poolB[base + 192];
    out[b * 1024 + h * 64 + c] = sA;
    out[b * 1024 + 512 + h * 64 + c] = sB;
  }
}

extern "C" void kernel_launch(void* const* d_in, const int* in_sizes, int n_in,
                              void* d_out, int out_size, void* d_ws, size_t ws_size,
                              hipStream_t stream) {
  const float* A  = (const float*)d_in[0];
  const float* B  = (const float*)d_in[1];
  const float* W1 = (const float*)d_in[2];
  const float* b1 = (const float*)d_in[3];
  const float* W2 = (const float*)d_in[4];
  const float* b2 = (const float*)d_in[5];
  const float* q  = (const float*)d_in[6];
  float* out = (float*)d_out;
  float* ws = (float*)d_ws;

  float* Ar      = ws;                 // 1,048,576 f
  float* Br      = ws + 1048576;       // 1,048,576 f
  float* Fpart   = ws + 2097152;       // 64*4*40*64 = 655,360 f
  float* Gpart   = ws + 2752512;       // 655,360 f
  float* cmn     = ws + 3407872;       // 1,600 f
  float* rowmean = ws + 3409472;       // 16,384 f
  float* colmean = ws + 3425856;       // 16,384 f
  float* b2a     = ws + 3442240;       // 16,384 f
  float* a2b     = ws + 3458624;       // 16,384 f
  float* poolA   = ws + 3475008;       // 16,384 f
  float* poolB   = ws + 3491392;       // 16,384 f  (end ~14.0 MB)

  gemm_coef_kernel<<<dim3(32, 8, 3), 256, 0, stream>>>(
      A, W1, b1, Ar, B, W2, b2, Br, cmn);
  moments_kernel<<<dim3(64, 2, 4), 256, 0, stream>>>(Ar, Br, Fpart, Gpart);
  finalize_kernel<<<dim3(64, 4), 512, 0, stream>>>(Ar, Br, Fpart, Gpart, cmn, q,
                                                   rowmean, colmean);
  softmax_pool_kernel<<<dim3(64, 4), 512, 0, stream>>>(
      rowmean, colmean, A, B, b2a, a2b, poolA, poolB);
  final_kernel<<<8, 256, 0, stream>>>(poolA, poolB, b2a, a2b, out);
}

// Round 20
// 65.418 us; speedup vs baseline: 1.0852x; 1.0630x over previous
//
#include <hip/hip_runtime.h>
#include <hip/hip_bf16.h>

#define LOG2E 1.4426950408889634f
#define SC2   2.8853900817779268f   // 2*log2(e)
#define CHEB_R 4.0f
#define CHEB_M 40
#define PI_F 3.14159265358979f

typedef __attribute__((ext_vector_type(8))) short short8b;
typedef __attribute__((ext_vector_type(4))) short short4b;
typedef __attribute__((ext_vector_type(4))) float f32x4;

__device__ __forceinline__ float fast_exp2(float x) {
#if __has_builtin(__builtin_amdgcn_exp2f)
  return __builtin_amdgcn_exp2f(x);
#else
  return exp2f(x);
#endif
}
__device__ __forceinline__ float fast_rcp(float x) {
#if __has_builtin(__builtin_amdgcn_rcpf)
  return __builtin_amdgcn_rcpf(x);
#else
  return 1.0f / x;
#endif
}
__device__ __forceinline__ short f2bf(float f) {
  __hip_bfloat16 h = __float2bfloat16(f);
  return *reinterpret_cast<short*>(&h);
}

// ---------------------------------------------------------------------------
// Stage 1: gemm (r12 core) + coef side-block.
// z<2: O = relu(X @ W^T + bias) via bf16 MFMA, 64x64 tile, dense f32 store.
// z==2 (block (0,0) only): 40x40 Chebyshev coefficients of tanh(x*y) on
// [0,R]^2.  FIXED vs r19: T-matrix via per-column recurrence (80 small-arg
// cosf only), and both dot-product phases unrolled x8 with 4 independent
// accumulators so LDS reads batch (latency was the ~30us sink).
// ---------------------------------------------------------------------------
__global__ __launch_bounds__(256) void gemm_coef_kernel(
    const float* __restrict__ Xa, const float* __restrict__ Wa,
    const float* __restrict__ ba, float* __restrict__ Oa,
    const float* __restrict__ Xb, const float* __restrict__ Wb,
    const float* __restrict__ bb, float* __restrict__ Ob,
    float* __restrict__ cmn) {
  __shared__ __align__(16) char smem_raw[52224];
  int t = threadIdx.x;

  if (blockIdx.z == 2) {
    if (blockIdx.x != 0 || blockIdx.y != 0) return;
    float* S = (float*)smem_raw;        // [80][80]
    float* T = S + 6400;                // [40][80]
    float* H = S + 9600;                // [40][80]
    float* cq = S + 12800;              // [80]
    float* xn = S + 12880;              // [80]
    if (t < 80) {
      float th = (2.f * t + 1.f) * (PI_F / 160.f);
      float cc = cosf(th);              // small arg only
      cq[t] = cc;
      xn[t] = CHEB_R * 0.5f * (1.f + cc);
    }
    __syncthreads();
    if (t < 80) {
      float c1 = cq[t];
      float tp = 1.f, tc = c1;
      T[0 * 80 + t] = 1.f;
      T[1 * 80 + t] = c1;
#pragma unroll
      for (int n = 2; n < CHEB_M; ++n) {
        float tn = fmaf(2.f * c1, tc, -tp);
        T[n * 80 + t] = tn;
        tp = tc; tc = tn;
      }
    }
    for (int e = t; e < 6400; e += 256) {
      int p = e / 80, qq = e - p * 80;
      float x = xn[p] * xn[qq];
      float ee = fast_exp2(x * SC2);            // e^{2x}
      S[e] = (ee - 1.f) * fast_rcp(ee + 1.f);   // tanh(x)
    }
    __syncthreads();
    for (int e = t; e < CHEB_M * 80; e += 256) {
      int n = e / 80, p = e - n * 80;
      const float* Tn = &T[n * 80];
      const float* Sp = &S[p * 80];
      float s0 = 0.f, s1 = 0.f, s2 = 0.f, s3 = 0.f;
#pragma unroll
      for (int qq = 0; qq < 80; qq += 8) {
        s0 = fmaf(Tn[qq + 0], Sp[qq + 0], s0);
        s1 = fmaf(Tn[qq + 1], Sp[qq + 1], s1);
        s2 = fmaf(Tn[qq + 2], Sp[qq + 2], s2);
        s3 = fmaf(Tn[qq + 3], Sp[qq + 3], s3);
        s0 = fmaf(Tn[qq + 4], Sp[qq + 4], s0);
        s1 = fmaf(Tn[qq + 5], Sp[qq + 5], s1);
        s2 = fmaf(Tn[qq + 6], Sp[qq + 6], s2);
        s3 = fmaf(Tn[qq + 7], Sp[qq + 7], s3);
      }
      H[n * 80 + p] = (s0 + s1) + (s2 + s3);
    }
    __syncthreads();
    for (int e = t; e < CHEB_M * CHEB_M; e += 256) {
      int m = e / CHEB_M, n = e - m * CHEB_M;
      const float* Tm = &T[m * 80];
      const float* Hn = &H[n * 80];
      float s0 = 0.f, s1 = 0.f, s2 = 0.f, s3 = 0.f;
#pragma unroll
      for (int p = 0; p < 80; p += 8) {
        s0 = fmaf(Tm[p + 0], Hn[p + 0], s0);
        s1 = fmaf(Tm[p + 1], Hn[p + 1], s1);
        s2 = fmaf(Tm[p + 2], Hn[p + 2], s2);
        s3 = fmaf(Tm[p + 3], Hn[p + 3], s3);
        s0 = fmaf(Tm[p + 4], Hn[p + 4], s0);
        s1 = fmaf(Tm[p + 5], Hn[p + 5], s1);
        s2 = fmaf(Tm[p + 6], Hn[p + 6], s2);
        s3 = fmaf(Tm[p + 7], Hn[p + 7], s3);
      }
      float wm = (m == 0) ? 1.f : 2.f;
      float wn = (n == 0) ? 1.f : 2.f;
      cmn[e] = ((s0 + s1) + (s2 + s3)) * (wm * wn / 6400.f);
    }
    return;
  }

  const int isB = blockIdx.z;
  const float* X = isB ? Xb : Xa;
  const float* W = isB ? Wb : Wa;
  const float* bias = isB ? bb : ba;
  float* O = isB ? Ob : Oa;

  short* As = (short*)smem_raw;          // 64 x 40 bf16
  short* Ws = As + 64 * 40;

  int m0 = blockIdx.x * 64, n0 = blockIdx.y * 64;
  int l = t & 63, w = t >> 6;
  int wm = (w >> 1) * 32, wn = (w & 1) * 32;
  int lr = l & 15, ko = (l >> 4) * 8;

  f32x4 acc[2][2];
#pragma unroll
  for (int m = 0; m < 2; ++m)
#pragma unroll
    for (int n = 0; n < 2; ++n) acc[m][n] = f32x4{0.f, 0.f, 0.f, 0.f};

  for (int k0 = 0; k0 < 512; k0 += 32) {
#pragma unroll
    for (int s = 0; s < 2; ++s) {
      int slot = t + s * 256;
      int row = slot >> 3, qd = (slot & 7) << 2;
      float4 v = *reinterpret_cast<const float4*>(&X[(m0 + row) * 512 + k0 + qd]);
      short4b sv = {f2bf(v.x), f2bf(v.y), f2bf(v.z), f2bf(v.w)};
      *reinterpret_cast<short4b*>(&As[row * 40 + qd]) = sv;
      float4 u = *reinterpret_cast<const float4*>(&W[(n0 + row) * 512 + k0 + qd]);
      short4b su = {f2bf(u.x), f2bf(u.y), f2bf(u.z), f2bf(u.w)};
      *reinterpret_cast<short4b*>(&Ws[row * 40 + qd]) = su;
    }
    __syncthreads();

    short8b afr[2], bfr[2];
#pragma unroll
    for (int m = 0; m < 2; ++m)
      afr[m] = *reinterpret_cast<const short8b*>(&As[(wm + m * 16 + lr) * 40 + ko]);
#pragma unroll
    for (int n = 0; n < 2; ++n)
      bfr[n] = *reinterpret_cast<const short8b*>(&Ws[(wn + n * 16 + lr) * 40 + ko]);
#pragma unroll
    for (int m = 0; m < 2; ++m)
#pragma unroll
      for (int n = 0; n < 2; ++n)
        acc[m][n] = __builtin_amdgcn_mfma_f32_16x16x32_bf16(afr[m], bfr[n], acc[m][n], 0, 0, 0);
    __syncthreads();
  }

#pragma unroll
  for (int n = 0; n < 2; ++n) {
    int col = n0 + wn + n * 16 + lr;
    float bv = bias[col];
#pragma unroll
    for (int m = 0; m < 2; ++m) {
      int rbase = m0 + wm + m * 16 + (l >> 4) * 4;
#pragma unroll
      for (int r = 0; r < 4; ++r) {
        float v = acc[m][n][r] + bv;
        O[(rbase + r) * 512 + col] = v > 0.f ? v : 0.f;
      }
    }
  }
}

// ---------------------------------------------------------------------------
// Stage 2 (moments, ILP-4; r19-verbatim): grid (64, 2, 4) x 256.
// ---------------------------------------------------------------------------
__global__ __launch_bounds__(256) void moments_kernel(
    const float* __restrict__ Ar, const float* __restrict__ Br,
    float* __restrict__ Fpart, float* __restrict__ Gpart) {
  __shared__ float red[4 * CHEB_M * 64];
  int t = threadIdx.x;
  int bh = blockIdx.x, half = blockIdx.y, quad = blockIdx.z;
  const float* X = half ? Br : Ar;
  float* Out = half ? Gpart : Fpart;
  int c = t & 63, colsel = t >> 6;
  int colhi = quad * 2 + (colsel & 1);
  int rowh = colsel >> 1;
  int rbase = (bh >> 3) * 256 + (bh & 7) * 32 + rowh * 16;
  const float* p = X + rbase * 512 + colhi * 64 + c;

  float acc[CHEB_M];
#pragma unroll
  for (int m = 0; m < CHEB_M; ++m) acc[m] = 0.f;

#pragma unroll 1
  for (int rr = 0; rr < 16; rr += 4) {
    float a0 = p[(rr + 0) * 512];
    float a1 = p[(rr + 1) * 512];
    float a2 = p[(rr + 2) * 512];
    float a3 = p[(rr + 3) * 512];
    float u0 = fminf(a0 * 0.5f - 1.f, 1.f);
    float u1 = fminf(a1 * 0.5f - 1.f, 1.f);
    float u2 = fminf(a2 * 0.5f - 1.f, 1.f);
    float u3 = fminf(a3 * 0.5f - 1.f, 1.f);
    acc[0] += 4.f;
    acc[1] += (u0 + u1) + (u2 + u3);
    float tp0 = 1.f, tc0 = u0, tp1 = 1.f, tc1 = u1;
    float tp2 = 1.f, tc2 = u2, tp3 = 1.f, tc3 = u3;
#pragma unroll
    for (int m = 2; m < CHEB_M; ++m) {
      float tn0 = fmaf(2.f * u0, tc0, -tp0);
      float tn1 = fmaf(2.f * u1, tc1, -tp1);
      float tn2 = fmaf(2.f * u2, tc2, -tp2);
      float tn3 = fmaf(2.f * u3, tc3, -tp3);
      acc[m] += (tn0 + tn1) + (tn2 + tn3);
      tp0 = tc0; tc0 = tn0; tp1 = tc1; tc1 = tn1;
      tp2 = tc2; tc2 = tn2; tp3 = tc3; tc3 = tn3;
    }
  }
#pragma unroll
  for (int m = 0; m < CHEB_M; ++m) red[(colsel * CHEB_M + m) * 64 + c] = acc[m];
  __syncthreads();
  for (int e = t; e < CHEB_M * 64; e += 256) {
    int m = e >> 6, cc = e & 63;
    float s = red[(0 * CHEB_M + m) * 64 + cc] + red[(1 * CHEB_M + m) * 64 + cc] +
              red[(2 * CHEB_M + m) * 64 + cc] + red[(3 * CHEB_M + m) * 64 + cc];
    Out[(((bh * 4 + quad) * CHEB_M) + m) * 64 + cc] = s;
  }
}

// ---------------------------------------------------------------------------
// Stage 3 (finalize): grid (64 bh, 4 qd) x 512.  Prep loop now ILP-4
// unrolled (batched LDS reads); main loops r19-verbatim.
// ---------------------------------------------------------------------------
__global__ __launch_bounds__(512) void finalize_kernel(
    const float* __restrict__ Ar, const float* __restrict__ Br,
    const float* __restrict__ Fpart, const float* __restrict__ Gpart,
    const float* __restrict__ cmn, const float* __restrict__ q,
    float* __restrict__ rowmean, float* __restrict__ colmean) {
  __shared__ float cs[CHEB_M * CHEB_M];
  __shared__ float Fs[CHEB_M * 64];
  __shared__ float Gs[CHEB_M * 64];
  __shared__ float gq[CHEB_M * 64];
  __shared__ float dq[CHEB_M * 64];

  int bh = blockIdx.x, qd = blockIdx.y;
  int t = threadIdx.x;

  for (int e = t; e < CHEB_M * CHEB_M; e += 512) cs[e] = cmn[e];
  for (int e = t; e < CHEB_M * 64; e += 512) {
    float f = 0.f, g = 0.f;
#pragma unroll
    for (int p = 0; p < 4; ++p) {
      f += Fpart[((bh * 4 + p) * CHEB_M) * 64 + e];
      g += Gpart[((bh * 4 + p) * CHEB_M) * 64 + e];
    }
    Fs[e] = f; Gs[e] = g;
  }
  __syncthreads();

  for (int e = t; e < CHEB_M * 64; e += 512) {
    int m = e >> 6, c = e & 63;
    float qc = q[c] * (1.f / 256.f);
    float sg0 = 0.f, sg1 = 0.f, sg2 = 0.f, sg3 = 0.f;
    float sd0 = 0.f, sd1 = 0.f, sd2 = 0.f, sd3 = 0.f;
#pragma unroll
    for (int n = 0; n < CHEB_M; n += 4) {
      sg0 = fmaf(cs[m * CHEB_M + n + 0], Gs[(n + 0) * 64 + c], sg0);
      sg1 = fmaf(cs[m * CHEB_M + n + 1], Gs[(n + 1) * 64 + c], sg1);
      sg2 = fmaf(cs[m * CHEB_M + n + 2], Gs[(n + 2) * 64 + c], sg2);
      sg3 = fmaf(cs[m * CHEB_M + n + 3], Gs[(n + 3) * 64 + c], sg3);
      sd0 = fmaf(cs[(n + 0) * CHEB_M + m], Fs[(n + 0) * 64 + c], sd0);
      sd1 = fmaf(cs[(n + 1) * CHEB_M + m], Fs[(n + 1) * 64 + c], sd1);
      sd2 = fmaf(cs[(n + 2) * CHEB_M + m], Fs[(n + 2) * 64 + c], sd2);
      sd3 = fmaf(cs[(n + 3) * CHEB_M + m], Fs[(n + 3) * 64 + c], sd3);
    }
    gq[e] = ((sg0 + sg1) + (sg2 + sg3)) * qc;
    dq[e] = ((sd0 + sd1) + (sd2 + sd3)) * qc;
  }
  __syncthreads();

  int rbase = (bh >> 3) * 256 + (bh & 7) * 32;
  // rows
  {
    int i = qd * 64 + (t >> 3);
    int ce = t & 7;
    const float* base = Ar + (rbase + (i >> 3)) * 512 + (i & 7) * 64 + ce * 8;
    float s0 = 0.f, s1 = 0.f, s2 = 0.f, s3 = 0.f;
#pragma unroll
    for (int g4 = 0; g4 < 2; ++g4) {
      int c0 = ce * 8 + g4 * 4;
      float a0 = base[g4 * 4 + 0], a1 = base[g4 * 4 + 1];
      float a2 = base[g4 * 4 + 2], a3 = base[g4 * 4 + 3];
      float u0 = fminf(a0 * 0.5f - 1.f, 1.f);
      float u1 = fminf(a1 * 0.5f - 1.f, 1.f);
      float u2 = fminf(a2 * 0.5f - 1.f, 1.f);
      float u3 = fminf(a3 * 0.5f - 1.f, 1.f);
      s0 += gq[c0 + 0]; s1 += gq[c0 + 1]; s2 += gq[c0 + 2]; s3 += gq[c0 + 3];
      s0 = fmaf(gq[64 + c0 + 0], u0, s0);
      s1 = fmaf(gq[64 + c0 + 1], u1, s1);
      s2 = fmaf(gq[64 + c0 + 2], u2, s2);
      s3 = fmaf(gq[64 + c0 + 3], u3, s3);
      float tp0 = 1.f, tc0 = u0, tp1 = 1.f, tc1 = u1;
      float tp2 = 1.f, tc2 = u2, tp3 = 1.f, tc3 = u3;
#pragma unroll
      for (int m = 2; m < CHEB_M; ++m) {
        float tn0 = fmaf(2.f * u0, tc0, -tp0);
        float tn1 = fmaf(2.f * u1, tc1, -tp1);
        float tn2 = fmaf(2.f * u2, tc2, -tp2);
        float tn3 = fmaf(2.f * u3, tc3, -tp3);
        s0 = fmaf(gq[m * 64 + c0 + 0], tn0, s0);
        s1 = fmaf(gq[m * 64 + c0 + 1], tn1, s1);
        s2 = fmaf(gq[m * 64 + c0 + 2], tn2, s2);
        s3 = fmaf(gq[m * 64 + c0 + 3], tn3, s3);
        tp0 = tc0; tc0 = tn0; tp1 = tc1; tc1 = tn1;
        tp2 = tc2; tc2 = tn2; tp3 = tc3; tc3 = tn3;
      }
    }
    float s = (s0 + s1) + (s2 + s3);
    s += __shfl_xor(s, 1);
    s += __shfl_xor(s, 2);
    s += __shfl_xor(s, 4);
    if ((t & 7) == 0) rowmean[bh * 256 + i] = s;
  }
  // cols
  {
    int j = qd * 64 + (t >> 3);
    int ce = t & 7;
    const float* base = Br + (rbase + (j >> 3)) * 512 + (j & 7) * 64 + ce * 8;
    float s0 = 0.f, s1 = 0.f, s2 = 0.f, s3 = 0.f;
#pragma unroll
    for (int g4 = 0; g4 < 2; ++g4) {
      int c0 = ce * 8 + g4 * 4;
      float a0 = base[g4 * 4 + 0], a1 = base[g4 * 4 + 1];
      float a2 = base[g4 * 4 + 2], a3 = base[g4 * 4 + 3];
      float u0 = fminf(a0 * 0.5f - 1.f, 1.f);
      float u1 = fminf(a1 * 0.5f - 1.f, 1.f);
      float u2 = fminf(a2 * 0.5f - 1.f, 1.f);
      float u3 = fminf(a3 * 0.5f - 1.f, 1.f);
      s0 += dq[c0 + 0]; s1 += dq[c0 + 1]; s2 += dq[c0 + 2]; s3 += dq[c0 + 3];
      s0 = fmaf(dq[64 + c0 + 0], u0, s0);
      s1 = fmaf(dq[64 + c0 + 1], u1, s1);
      s2 = fmaf(dq[64 + c0 + 2], u2, s2);
      s3 = fmaf(dq[64 + c0 + 3], u3, s3);
      float tp0 = 1.f, tc0 = u0, tp1 = 1.f, tc1 = u1;
      float tp2 = 1.f, tc2 = u2, tp3 = 1.f, tc3 = u3;
#pragma unroll
      for (int m = 2; m < CHEB_M; ++m) {
        float tn0 = fmaf(2.f * u0, tc0, -tp0);
        float tn1 = fmaf(2.f * u1, tc1, -tp1);
        float tn2 = fmaf(2.f * u2, tc2, -tp2);
        float tn3 = fmaf(2.f * u3, tc3, -tp3);
        s0 = fmaf(dq[m * 64 + c0 + 0], tn0, s0);
        s1 = fmaf(dq[m * 64 + c0 + 1], tn1, s1);
        s2 = fmaf(dq[m * 64 + c0 + 2], tn2, s2);
        s3 = fmaf(dq[m * 64 + c0 + 3], tn3, s3);
        tp0 = tc0; tc0 = tn0; tp1 = tc1; tc1 = tn1;
        tp2 = tc2; tc2 = tn2; tp3 = tc3; tc3 = tn3;
      }
    }
    float s = (s0 + s1) + (s2 + s3);
    s += __shfl_xor(s, 1);
    s += __shfl_xor(s, 2);
    s += __shfl_xor(s, 4);
    if ((t & 7) == 0) colmean[bh * 256 + j] = s;
  }
}

// ---------------------------------------------------------------------------
// Stage 4 (r12-proven): grid (64 bh, 4 chunk), 512 thr.
// ---------------------------------------------------------------------------
__global__ __launch_bounds__(512) void softmax_pool_kernel(
    const float* __restrict__ rowmean, const float* __restrict__ colmean,
    const float* __restrict__ A0, const float* __restrict__ B0,
    float* __restrict__ b2a, float* __restrict__ a2b,
    float* __restrict__ poolA, float* __restrict__ poolB) {
  int bh = blockIdx.x, chunk = blockIdx.y;
  int b = bh >> 3, h = bh & 7;
  int t = threadIdx.x;
  int tt = t & 255;
  int lane = t & 63, w = (t >> 6) & 3;
  __shared__ float redA[4], redB[4], redC[4], redD[4];
  __shared__ float tA[256], tB[256];
  __shared__ float pp[8][64];

  float r = rowmean[bh * 256 + tt];
  float cs = colmean[bh * 256 + tt];

  float mr = r, mc = cs;
#pragma unroll
  for (int off = 32; off >= 1; off >>= 1) {
    mr = fmaxf(mr, __shfl_xor(mr, off));
    mc = fmaxf(mc, __shfl_xor(mc, off));
  }
  if (lane == 0) { redA[w] = mr; redB[w] = mc; }
  __syncthreads();
  mr = fmaxf(fmaxf(redA[0], redA[1]), fmaxf(redA[2], redA[3]));
  mc = fmaxf(fmaxf(redB[0], redB[1]), fmaxf(redB[2], redB[3]));

  float er = fast_exp2((r - mr) * LOG2E);
  float ec = fast_exp2((cs - mc) * LOG2E);
  float sr = er, sc = ec;
#pragma unroll
  for (int off = 32; off >= 1; off >>= 1) {
    sr += __shfl_xor(sr, off);
    sc += __shfl_xor(sc, off);
  }
  if (lane == 0) { redC[w] = sr; redD[w] = sc; }
  __syncthreads();
  sr = redC[0] + redC[1] + redC[2] + redC[3];
  sc = redD[0] + redD[1] + redD[2] + redD[3];

  float vb2a = er * fast_rcp(sr);
  float va2b = ec * fast_rcp(sc);
  tA[tt] = vb2a; tB[tt] = va2b;
  if (chunk == 0) {
    b2a[bh * 256 + tt] = vb2a;
    a2b[bh * 256 + tt] = va2b;
  }
  __syncthreads();

  int c = t & 63, isub = t >> 6;
  const float* Ab = A0 + b * 131072 + h * 16384;
  const float* Bb = B0 + b * 131072 + h * 16384;
  float pa = 0.f, pb = 0.f;
#pragma unroll
  for (int ii = 0; ii < 8; ++ii) {
    int i = chunk * 64 + isub * 8 + ii;
    pa = fmaf(Ab[i * 64 + c], tA[i], pa);
    pb = fmaf(Bb[i * 64 + c], tB[i], pb);
  }
  pp[isub][c] = pa;
  __syncthreads();
  if (t < 64) {
    float s = 0.f;
#pragma unroll
    for (int k = 0; k < 8; ++k) s += pp[k][t];
    poolA[(bh * 4 + chunk) * 64 + t] = s;
  }
  __syncthreads();
  pp[isub][c] = pb;
  __syncthreads();
  if (t < 64) {
    float s = 0.f;
#pragma unroll
    for (int k = 0; k < 8; ++k) s += pp[k][t];
    poolB[(bh * 4 + chunk) * 64 + t] = s;
  }
}

// ---------------------------------------------------------------------------
// Stage 5 (r12-verbatim): combine pool partials + head-means.  grid 8 x 256.
// ---------------------------------------------------------------------------
__global__ __launch_bounds__(256) void final_kernel(
    const float* __restrict__ poolA, const float* __restrict__ poolB,
    const float* __restrict__ b2a, const float* __restrict__ a2b,
    float* __restrict__ out) {
  int b = blockIdx.x, t = threadIdx.x;
  float s1 = 0.f, s2 = 0.f;
#pragma unroll
  for (int h = 0; h < 8; ++h) {
    s1 += b2a[(b * 8 + h) * 256 + t];
    s2 += a2b[(b * 8 + h) * 256 + t];
  }
  out[8192 + b * 256 + t] = s1 * 0.125f;
  out[10240 + b * 256 + t] = s2 * 0.125f;

#pragma unroll
  for (int hh = 0; hh < 2; ++hh) {
    int idx = hh * 256 + t;
    int h = idx >> 6, c = idx & 63;
    int base = ((b * 8 + h) * 4) * 64 + c;
    float sA = poolA[base] + poolA[base + 64] + poolA[base + 128] + poolA[base + 192];
    float sB = poolB[base] + poolB[base + 64] + poolB[base + 128] + poolB[base + 192];
    out[b * 1024 + h * 64 + c] = sA;
    out[b * 1024 + 512 + h * 64 + c] = sB;
  }
}

extern "C" void kernel_launch(void* const* d_in, const int* in_sizes, int n_in,
                              void* d_out, int out_size, void* d_ws, size_t ws_size,
                              hipStream_t stream) {
  const float* A  = (const float*)d_in[0];
  const float* B  = (const float*)d_in[1];
  const float* W1 = (const float*)d_in[2];
  const float* b1 = (const float*)d_in[3];
  const float* W2 = (const float*)d_in[4];
  const float* b2 = (const float*)d_in[5];
  const float* q  = (const float*)d_in[6];
  float* out = (float*)d_out;
  float* ws = (float*)d_ws;

  float* Ar      = ws;                 // 1,048,576 f
  float* Br      = ws + 1048576;       // 1,048,576 f
  float* Fpart   = ws + 2097152;       // 655,360 f
  float* Gpart   = ws + 2752512;       // 655,360 f
  float* cmn     = ws + 3407872;       // 1,600 f
  float* rowmean = ws + 3409472;       // 16,384 f
  float* colmean = ws + 3425856;       // 16,384 f
  float* b2a     = ws + 3442240;       // 16,384 f
  float* a2b     = ws + 3458624;       // 16,384 f
  float* poolA   = ws + 3475008;       // 16,384 f
  float* poolB   = ws + 3491392;       // 16,384 f  (end ~14.0 MB)

  gemm_coef_kernel<<<dim3(32, 8, 3), 256, 0, stream>>>(
      A, W1, b1, Ar, B, W2, b2, Br, cmn);
  moments_kernel<<<dim3(64, 2, 4), 256, 0, stream>>>(Ar, Br, Fpart, Gpart);
  finalize_kernel<<<dim3(64, 4), 512, 0, stream>>>(Ar, Br, Fpart, Gpart, cmn, q,
                                                   rowmean, colmean);
  softmax_pool_kernel<<<dim3(64, 4), 512, 0, stream>>>(
      rowmean, colmean, A, B, b2a, a2b, poolA, poolB);
  final_kernel<<<8, 256, 0, stream>>>(poolA, poolB, b2a, a2b, out);
}